// Round 7
// baseline (18.405 us; speedup 1.0000x reference)
//
#include <hip/hip_runtime.h>

#define NGRAPH 680    // 120 vars + 105 h-factors + 455 g-factors

// pair index for a<b among N=15
__device__ __forceinline__ int pair_index(int a, int b) {
    return a * (29 - a) / 2 + (b - a - 1);
}

// ---- compile-time structure tables (graph is fixed) -----------------------
struct PairTab { unsigned char u[105]; unsigned char v[105]; };
__device__ constexpr PairTab make_pair_tab() {
    PairTab t{};
    int f = 0;
    for (int a = 0; a < 15; a++)
        for (int b = a + 1; b < 15; b++) { t.u[f] = (unsigned char)a; t.v[f] = (unsigned char)b; f++; }
    return t;
}
__device__ constexpr PairTab PAIRS = make_pair_tab();

struct TriTab { unsigned char z1[455]; unsigned char z2[455]; unsigned char z3[455]; };
__device__ constexpr TriTab make_tri_tab() {
    TriTab t{};
    int n = 0;
    for (int i = 0; i < 15; i++)
        for (int j = i + 1; j < 15; j++)
            for (int k = j + 1; k < 15; k++) {
                t.z1[n] = (unsigned char)(15 + i * (29 - i) / 2 + (j - i - 1));
                t.z2[n] = (unsigned char)(15 + i * (29 - i) / 2 + (k - i - 1));
                t.z3[n] = (unsigned char)(15 + j * (29 - j) / 2 + (k - j - 1));
                n++;
            }
    return t;
}
__device__ constexpr TriTab TRI = make_tri_tab();

// Grid: 1024 = (col c 0..15) x (batch 0..63), batch minor: all 16 blocks of a
// batch land on XCD b%8 (vf L2-reuse, output-line merging in L2).
// 256 threads, 2 barriers.
//  phase 0: stage W column c, both halves, COL-MAJOR Wl[2][128] (1 float/thr)
//  phase 1: thread (r, g) computes P[r, c] half g: 32 float4 vf loads +
//           32 broadcast ds_read_b128 + 128 FMA in 4 independent chains.
//  phase 2: 680 rows x 1 col; TH recomputed inline (no 3rd barrier).
__global__ __launch_bounds__(256) void fgnn_fused(
    const float* __restrict__ vf,    // [64][120][128]
    const float* __restrict__ W,     // [256][16]
    const float* __restrict__ bias,  // [16]
    float* __restrict__ out)         // [64][680][16]
{
    __shared__ float Wl[2][128];   // [half g][k]  (col-major slice of W)
    __shared__ float Ps[120];      // self  P column (bias folded)
    __shared__ float Pt[120];      // neighbor P column

    const int tid = threadIdx.x;
    const int c   = blockIdx.x >> 6;   // output column 0..15
    const int b   = blockIdx.x & 63;   // batch

    // ---- phase 0: stage W[:, c] (256 values, 1 per thread) ----------------
    ((float*)Wl)[tid] = W[tid * 16 + c];
    __syncthreads();

    // ---- phase 1: P[r, c] for both halves ----------------------------------
    const int r = tid >> 1;
    const int g = tid & 1;             // 0 = S half, 1 = T half
    if (r < 120) {
        const float4* va = (const float4*)(vf + ((size_t)b * 120 + r) * 128);
        const float4* wk = (const float4*)&Wl[g][0];
        float a0 = 0.f, a1 = 0.f, a2 = 0.f, a3 = 0.f;
        #pragma unroll
        for (int k4 = 0; k4 < 32; k4++) {
            float4 a = va[k4];
            float4 w = wk[k4];
            a0 = fmaf(a.x, w.x, a0);
            a1 = fmaf(a.y, w.y, a1);
            a2 = fmaf(a.z, w.z, a2);
            a3 = fmaf(a.w, w.w, a3);
        }
        float sum = (a0 + a1) + (a2 + a3);
        if (g == 0) Ps[r] = sum + bias[c];
        else        Pt[r] = sum;
    }
    __syncthreads();

    // ---- phase 2: 680 rows x 1 col ------------------------------------------
    const float inv3  = 1.0f / 3.0f;
    const float inv14 = 1.0f / 14.0f;
    float* outb = out + (size_t)b * NGRAPH * 16 + c;

    for (int i = tid; i < NGRAPH; i += 256) {
        float res;
        if (i < 15) {
            // person u: 14 h-factor neighbors; Pt[i] hoisted
            float s0  = Ps[i];
            float pti = Pt[i];
            float acc = 0.f;
            #pragma unroll
            for (int v2 = 0; v2 < 15; v2++) {
                if (v2 == i) continue;
                int z = 15 + pair_index(min(i, v2), max(i, v2));
                acc += fmaxf(s0 + (pti + Pt[v2] + Pt[z]) * inv3, 0.f);
            }
            res = acc * inv14;
        } else if (i < 120) {
            // pair z-node: 1 h-factor + 13 g-factors
            int f = i - 15;
            int u = PAIRS.u[f], v = PAIRS.v[f];
            float s0 = Ps[i];
            float tz = Pt[i];
            float acc = fmaxf(s0 + (Pt[u] + Pt[v] + tz) * inv3, 0.f);
            #pragma unroll
            for (int w = 0; w < 15; w++) {
                if (w == u || w == v) continue;
                int zuw = 15 + pair_index(min(u, w), max(u, w));
                int zvw = 15 + pair_index(min(v, w), max(v, w));
                acc += fmaxf(s0 + (tz + Pt[zuw] + Pt[zvw]) * inv3, 0.f);
            }
            res = acc * inv14;
        } else if (i < 225) {
            // h-factor row: neighbors [u, v, z x12]
            int f = i - 120;
            int u = PAIRS.u[f], v = PAIRS.v[f], z = 15 + f;
            float S = (Ps[u] + Ps[v] + Ps[z]) * inv3;
            res = (fmaxf(S + Pt[u], 0.f) + fmaxf(S + Pt[v], 0.f)
                 + 12.f * fmaxf(S + Pt[z], 0.f)) * inv14;
        } else {
            // g-factor row: neighbors [z1, z2, z3 x12]
            int t3 = i - 225;
            int z1 = TRI.z1[t3], z2 = TRI.z2[t3], z3 = TRI.z3[t3];
            float S = (Ps[z1] + Ps[z2] + Ps[z3]) * inv3;
            res = (fmaxf(S + Pt[z1], 0.f) + fmaxf(S + Pt[z2], 0.f)
                 + 12.f * fmaxf(S + Pt[z3], 0.f)) * inv14;
        }
        outb[(size_t)i * 16] = res;
    }
}

extern "C" void kernel_launch(void* const* d_in, const int* in_sizes, int n_in,
                              void* d_out, int out_size, void* d_ws, size_t ws_size,
                              hipStream_t stream) {
    const float* vf   = (const float*)d_in[0];  // [64,120,128]
    const float* W    = (const float*)d_in[1];  // [256,16]
    const float* bias = (const float*)d_in[2];  // [16]
    float* o = (float*)d_out;                   // [64,680,16]

    fgnn_fused<<<1024, 256, 0, stream>>>(vf, W, bias, o);
}

// Round 8
// 14.872 us; speedup vs baseline: 1.2376x; 1.2376x over previous
//
#include <hip/hip_runtime.h>

#define NGRAPH 680    // 120 vars + 105 h-factors + 455 g-factors

// pair index for a<b among N=15
__device__ __forceinline__ int pair_index(int a, int b) {
    return a * (29 - a) / 2 + (b - a - 1);
}

// ---- compile-time structure tables (graph is fixed) -----------------------
struct PairTab { unsigned char u[105]; unsigned char v[105]; };
__device__ constexpr PairTab make_pair_tab() {
    PairTab t{};
    int f = 0;
    for (int a = 0; a < 15; a++)
        for (int b = a + 1; b < 15; b++) { t.u[f] = (unsigned char)a; t.v[f] = (unsigned char)b; f++; }
    return t;
}
__device__ constexpr PairTab PAIRS = make_pair_tab();

struct TriTab { unsigned char z1[455]; unsigned char z2[455]; unsigned char z3[455]; };
__device__ constexpr TriTab make_tri_tab() {
    TriTab t{};
    int n = 0;
    for (int i = 0; i < 15; i++)
        for (int j = i + 1; j < 15; j++)
            for (int k = j + 1; k < 15; k++) {
                t.z1[n] = (unsigned char)(15 + i * (29 - i) / 2 + (j - i - 1));
                t.z2[n] = (unsigned char)(15 + i * (29 - i) / 2 + (k - i - 1));
                t.z3[n] = (unsigned char)(15 + j * (29 - j) / 2 + (k - j - 1));
                n++;
            }
    return t;
}
__device__ constexpr TriTab TRI = make_tri_tab();

// R4 structure (best so far, 14.53us) with ONE change: W staged col-pair-
// interleaved so phase 1 reads it as 64 ds_read_b128 instead of 128 b64.
// Grid: 512 = (col-pair s 0..7) x (batch 0..63), batch minor (XCD locality).
// 512 threads/block; no redundant GEMM work.
__global__ __launch_bounds__(512) void fgnn_fused(
    const float* __restrict__ vf,    // [64][120][128]
    const float* __restrict__ W,     // [256][16]
    const float* __restrict__ bias,  // [16]
    float* __restrict__ out)         // [64][680][16]
{
    __shared__ float Wl[2][128][2];  // [half g][k][col j]
    __shared__ float Ps[120][2];
    __shared__ float Pt[120][2];
    __shared__ float TH[105][2];

    const int tid = threadIdx.x;
    const int s   = blockIdx.x >> 6;   // col-pair
    const int b   = blockIdx.x & 63;   // batch
    const int c0  = s * 2;

    // ---- phase 0: stage W slice, interleaved by output column -------------
    {
        int j = tid & 1;
        int k = (tid >> 1) & 127;
        int g = tid >> 8;
        Wl[g][k][j] = W[(g * 128 + k) * 16 + c0 + j];
    }
    __syncthreads();

    // ---- phase 1: P[r, c0:c0+2] for S and T halves -------------------------
    if (tid < 240) {
        const int r = tid >> 1;
        const int g = tid & 1;          // 0 = S, 1 = T
        const float4* va = (const float4*)(vf + ((size_t)b * 120 + r) * 128);
        const float4* wq = (const float4*)&Wl[g][0][0];  // {k, k+1} x {j0, j1}
        float a0 = 0.f, a1 = 0.f;
        #pragma unroll
        for (int k4 = 0; k4 < 32; k4++) {
            float4 a  = va[k4];
            float4 w0 = wq[2 * k4];      // cols j0,j1 at k=4k4, 4k4+1
            float4 w1 = wq[2 * k4 + 1];  // cols j0,j1 at k=4k4+2, 4k4+3
            a0 = fmaf(a.x, w0.x, a0); a1 = fmaf(a.x, w0.y, a1);
            a0 = fmaf(a.y, w0.z, a0); a1 = fmaf(a.y, w0.w, a1);
            a0 = fmaf(a.z, w1.x, a0); a1 = fmaf(a.z, w1.y, a1);
            a0 = fmaf(a.w, w1.z, a0); a1 = fmaf(a.w, w1.w, a1);
        }
        if (g == 0) {
            Ps[r][0] = a0 + bias[c0];
            Ps[r][1] = a1 + bias[c0 + 1];
        } else {
            Pt[r][0] = a0;
            Pt[r][1] = a1;
        }
    }
    __syncthreads();

    // ---- phase 1.5: h-factor T-means (3x reuse) ----------------------------
    if (tid < 210) {
        int f = tid >> 1, c = tid & 1;
        TH[f][c] = (Pt[PAIRS.u[f]][c] + Pt[PAIRS.v[f]][c] + Pt[15 + f][c]) * (1.0f / 3.0f);
    }
    __syncthreads();

    // ---- phase 2: 680 rows x 2 cols ----------------------------------------
    const float inv3  = 1.0f / 3.0f;
    const float inv14 = 1.0f / 14.0f;
    float* outb = out + (size_t)b * NGRAPH * 16 + c0;

    for (int i = tid; i < NGRAPH; i += 512) {
        float r0, r1;
        if (i < 15) {
            // person u: 14 h-factor neighbors
            float s0 = Ps[i][0], s1 = Ps[i][1];
            float acc0 = 0.f, acc1 = 0.f;
            #pragma unroll
            for (int v2 = 0; v2 < 15; v2++) {
                if (v2 == i) continue;
                int f = pair_index(min(i, v2), max(i, v2));
                acc0 += fmaxf(s0 + TH[f][0], 0.f);
                acc1 += fmaxf(s1 + TH[f][1], 0.f);
            }
            r0 = acc0 * inv14; r1 = acc1 * inv14;
        } else if (i < 120) {
            // pair z-node: 1 h-factor + 13 g-factors
            int f = i - 15;
            int u = PAIRS.u[f], v = PAIRS.v[f];
            float s0 = Ps[i][0], s1 = Ps[i][1];
            float t0 = Pt[i][0], t1 = Pt[i][1];
            float acc0 = fmaxf(s0 + TH[f][0], 0.f);
            float acc1 = fmaxf(s1 + TH[f][1], 0.f);
            #pragma unroll
            for (int w = 0; w < 15; w++) {
                if (w == u || w == v) continue;
                int zuw = 15 + pair_index(min(u, w), max(u, w));
                int zvw = 15 + pair_index(min(v, w), max(v, w));
                acc0 += fmaxf(s0 + (t0 + Pt[zuw][0] + Pt[zvw][0]) * inv3, 0.f);
                acc1 += fmaxf(s1 + (t1 + Pt[zuw][1] + Pt[zvw][1]) * inv3, 0.f);
            }
            r0 = acc0 * inv14; r1 = acc1 * inv14;
        } else if (i < 225) {
            // h-factor row: neighbors [u, v, z x12]
            int f = i - 120;
            int u = PAIRS.u[f], v = PAIRS.v[f], z = 15 + f;
            float S0 = (Ps[u][0] + Ps[v][0] + Ps[z][0]) * inv3;
            float S1 = (Ps[u][1] + Ps[v][1] + Ps[z][1]) * inv3;
            r0 = (fmaxf(S0 + Pt[u][0], 0.f) + fmaxf(S0 + Pt[v][0], 0.f)
                + 12.f * fmaxf(S0 + Pt[z][0], 0.f)) * inv14;
            r1 = (fmaxf(S1 + Pt[u][1], 0.f) + fmaxf(S1 + Pt[v][1], 0.f)
                + 12.f * fmaxf(S1 + Pt[z][1], 0.f)) * inv14;
        } else {
            // g-factor row: neighbors [z1, z2, z3 x12]
            int t3 = i - 225;
            int z1 = TRI.z1[t3], z2 = TRI.z2[t3], z3 = TRI.z3[t3];
            float S0 = (Ps[z1][0] + Ps[z2][0] + Ps[z3][0]) * inv3;
            float S1 = (Ps[z1][1] + Ps[z2][1] + Ps[z3][1]) * inv3;
            r0 = (fmaxf(S0 + Pt[z1][0], 0.f) + fmaxf(S0 + Pt[z2][0], 0.f)
                + 12.f * fmaxf(S0 + Pt[z3][0], 0.f)) * inv14;
            r1 = (fmaxf(S1 + Pt[z1][1], 0.f) + fmaxf(S1 + Pt[z2][1], 0.f)
                + 12.f * fmaxf(S1 + Pt[z3][1], 0.f)) * inv14;
        }
        *(float2*)(outb + (size_t)i * 16) = make_float2(r0, r1);
    }
}

extern "C" void kernel_launch(void* const* d_in, const int* in_sizes, int n_in,
                              void* d_out, int out_size, void* d_ws, size_t ws_size,
                              hipStream_t stream) {
    const float* vf   = (const float*)d_in[0];  // [64,120,128]
    const float* W    = (const float*)d_in[1];  // [256,16]
    const float* bias = (const float*)d_in[2];  // [16]
    float* o = (float*)d_out;                   // [64,680,16]

    fgnn_fused<<<512, 512, 0, stream>>>(vf, W, bias, o);
}

// Round 9
// 14.284 us; speedup vs baseline: 1.2886x; 1.0412x over previous
//
#include <hip/hip_runtime.h>

#define NGRAPH 680    // 120 vars + 105 h-factors + 455 g-factors

// pair index for a<b among N=15
__device__ __forceinline__ int pair_index(int a, int b) {
    return a * (29 - a) / 2 + (b - a - 1);
}

// ---- compile-time structure tables (graph is fixed) -----------------------
struct PairTab { unsigned char u[105]; unsigned char v[105]; };
__device__ constexpr PairTab make_pair_tab() {
    PairTab t{};
    int f = 0;
    for (int a = 0; a < 15; a++)
        for (int b = a + 1; b < 15; b++) { t.u[f] = (unsigned char)a; t.v[f] = (unsigned char)b; f++; }
    return t;
}
__device__ constexpr PairTab PAIRS = make_pair_tab();

struct TriTab { unsigned char z1[455]; unsigned char z2[455]; unsigned char z3[455]; };
__device__ constexpr TriTab make_tri_tab() {
    TriTab t{};
    int n = 0;
    for (int i = 0; i < 15; i++)
        for (int j = i + 1; j < 15; j++)
            for (int k = j + 1; k < 15; k++) {
                t.z1[n] = (unsigned char)(15 + i * (29 - i) / 2 + (j - i - 1));
                t.z2[n] = (unsigned char)(15 + i * (29 - i) / 2 + (k - i - 1));
                t.z3[n] = (unsigned char)(15 + j * (29 - j) / 2 + (k - j - 1));
                n++;
            }
    return t;
}
__device__ constexpr TriTab TRI = make_tri_tab();

// R4 structure (best, 14.53us) with ONE change: the TH stage + its barrier
// are removed; h-factor T-means are recomputed inline at use sites (3 LDS
// broadcast reads instead of 1 -- only ~130 threads affected, 3x fewer
// barriers block-wide). 2 barriers total.
// Grid: 512 = (col-pair s 0..7) x (batch 0..63), batch minor (XCD locality).
__global__ __launch_bounds__(512) void fgnn_fused(
    const float* __restrict__ vf,    // [64][120][128]
    const float* __restrict__ W,     // [256][16]
    const float* __restrict__ bias,  // [16]
    float* __restrict__ out)         // [64][680][16]
{
    __shared__ float Wl[128][4];   // [k][S0,S1,T0,T1]
    __shared__ float Ps[120][2];
    __shared__ float Pt[120][2];

    const int tid = threadIdx.x;
    const int s   = blockIdx.x >> 6;   // col-pair
    const int b   = blockIdx.x & 63;   // batch
    const int c0  = s * 2;

    // ---- phase 0: stage W slice --------------------------------------------
    if (tid < 128) {
        float2 ws = *(const float2*)(W + tid * 16 + c0);            // S half
        float2 wt = *(const float2*)(W + (128 + tid) * 16 + c0);    // T half
        Wl[tid][0] = ws.x; Wl[tid][1] = ws.y;
        Wl[tid][2] = wt.x; Wl[tid][3] = wt.y;
    }
    __syncthreads();

    // ---- phase 1: P[r, c0:c0+2] for S and T halves -------------------------
    if (tid < 240) {
        const int r = tid >> 1;
        const int g = tid & 1;          // 0 = S, 1 = T
        const float4* va   = (const float4*)(vf + ((size_t)b * 120 + r) * 128);
        const float2* wcol = (const float2*)&Wl[0][g * 2];  // stride 2 float2/row
        float a0 = 0.f, a1 = 0.f;
        #pragma unroll
        for (int k4 = 0; k4 < 32; k4++) {
            float4 a  = va[k4];
            float2 w0 = wcol[(4 * k4 + 0) * 2];
            float2 w1 = wcol[(4 * k4 + 1) * 2];
            float2 w2 = wcol[(4 * k4 + 2) * 2];
            float2 w3 = wcol[(4 * k4 + 3) * 2];
            a0 = fmaf(a.x, w0.x, a0); a1 = fmaf(a.x, w0.y, a1);
            a0 = fmaf(a.y, w1.x, a0); a1 = fmaf(a.y, w1.y, a1);
            a0 = fmaf(a.z, w2.x, a0); a1 = fmaf(a.z, w2.y, a1);
            a0 = fmaf(a.w, w3.x, a0); a1 = fmaf(a.w, w3.y, a1);
        }
        if (g == 0) {
            Ps[r][0] = a0 + bias[c0];
            Ps[r][1] = a1 + bias[c0 + 1];
        } else {
            Pt[r][0] = a0;
            Pt[r][1] = a1;
        }
    }
    __syncthreads();

    // ---- phase 2: 680 rows x 2 cols (TH inlined, no extra barrier) ---------
    const float inv3  = 1.0f / 3.0f;
    const float inv14 = 1.0f / 14.0f;
    float* outb = out + (size_t)b * NGRAPH * 16 + c0;

    for (int i = tid; i < NGRAPH; i += 512) {
        float r0, r1;
        if (i < 15) {
            // person u: 14 h-factor neighbors; TH inline
            float s0 = Ps[i][0], s1 = Ps[i][1];
            float p0 = Pt[i][0], p1 = Pt[i][1];
            float acc0 = 0.f, acc1 = 0.f;
            #pragma unroll
            for (int v2 = 0; v2 < 15; v2++) {
                if (v2 == i) continue;
                int z = 15 + pair_index(min(i, v2), max(i, v2));
                acc0 += fmaxf(s0 + (p0 + Pt[v2][0] + Pt[z][0]) * inv3, 0.f);
                acc1 += fmaxf(s1 + (p1 + Pt[v2][1] + Pt[z][1]) * inv3, 0.f);
            }
            r0 = acc0 * inv14; r1 = acc1 * inv14;
        } else if (i < 120) {
            // pair z-node: 1 h-factor + 13 g-factors
            int f = i - 15;
            int u = PAIRS.u[f], v = PAIRS.v[f];
            float s0 = Ps[i][0], s1 = Ps[i][1];
            float t0 = Pt[i][0], t1 = Pt[i][1];
            float acc0 = fmaxf(s0 + (Pt[u][0] + Pt[v][0] + t0) * inv3, 0.f);
            float acc1 = fmaxf(s1 + (Pt[u][1] + Pt[v][1] + t1) * inv3, 0.f);
            #pragma unroll
            for (int w = 0; w < 15; w++) {
                if (w == u || w == v) continue;
                int zuw = 15 + pair_index(min(u, w), max(u, w));
                int zvw = 15 + pair_index(min(v, w), max(v, w));
                acc0 += fmaxf(s0 + (t0 + Pt[zuw][0] + Pt[zvw][0]) * inv3, 0.f);
                acc1 += fmaxf(s1 + (t1 + Pt[zuw][1] + Pt[zvw][1]) * inv3, 0.f);
            }
            r0 = acc0 * inv14; r1 = acc1 * inv14;
        } else if (i < 225) {
            // h-factor row: neighbors [u, v, z x12]
            int f = i - 120;
            int u = PAIRS.u[f], v = PAIRS.v[f], z = 15 + f;
            float S0 = (Ps[u][0] + Ps[v][0] + Ps[z][0]) * inv3;
            float S1 = (Ps[u][1] + Ps[v][1] + Ps[z][1]) * inv3;
            r0 = (fmaxf(S0 + Pt[u][0], 0.f) + fmaxf(S0 + Pt[v][0], 0.f)
                + 12.f * fmaxf(S0 + Pt[z][0], 0.f)) * inv14;
            r1 = (fmaxf(S1 + Pt[u][1], 0.f) + fmaxf(S1 + Pt[v][1], 0.f)
                + 12.f * fmaxf(S1 + Pt[z][1], 0.f)) * inv14;
        } else {
            // g-factor row: neighbors [z1, z2, z3 x12]
            int t3 = i - 225;
            int z1 = TRI.z1[t3], z2 = TRI.z2[t3], z3 = TRI.z3[t3];
            float S0 = (Ps[z1][0] + Ps[z2][0] + Ps[z3][0]) * inv3;
            float S1 = (Ps[z1][1] + Ps[z2][1] + Ps[z3][1]) * inv3;
            r0 = (fmaxf(S0 + Pt[z1][0], 0.f) + fmaxf(S0 + Pt[z2][0], 0.f)
                + 12.f * fmaxf(S0 + Pt[z3][0], 0.f)) * inv14;
            r1 = (fmaxf(S1 + Pt[z1][1], 0.f) + fmaxf(S1 + Pt[z2][1], 0.f)
                + 12.f * fmaxf(S1 + Pt[z3][1], 0.f)) * inv14;
        }
        *(float2*)(outb + (size_t)i * 16) = make_float2(r0, r1);
    }
}

extern "C" void kernel_launch(void* const* d_in, const int* in_sizes, int n_in,
                              void* d_out, int out_size, void* d_ws, size_t ws_size,
                              hipStream_t stream) {
    const float* vf   = (const float*)d_in[0];  // [64,120,128]
    const float* W    = (const float*)d_in[1];  // [256,16]
    const float* bias = (const float*)d_in[2];  // [16]
    float* o = (float*)d_out;                   // [64,680,16]

    fgnn_fused<<<512, 512, 0, stream>>>(vf, W, bias, o);
}